// Round 7
// baseline (1796.562 us; speedup 1.0000x reference)
//
#include <hip/hip_runtime.h>
#include <hip/hip_fp16.h>
#include <math.h>

#define T_STEPS 12
#define N_NODES 512
#define FIN 32
#define FOUT 8
#define E_EDGES 16384
#define HDIM 4096    // N_NODES * FOUT
#define H4 16384     // 4 * HDIM

__device__ __forceinline__ float sigmoidf_(float x) { return 1.0f / (1.0f + __expf(-x)); }

// non-temporal 16B load: __builtin_nontemporal_load requires a scalar/Clang-vector
// type -- HIP's float4 is a class, so go through an ext_vector_type.
typedef float floatx4 __attribute__((ext_vector_type(4)));
__device__ __forceinline__ float4 ntload4(const float4* p) {
    floatx4 v = __builtin_nontemporal_load((const floatx4*)p);
    return make_float4(v.x, v.y, v.z, v.w);
}

// ---------------- GCN: one block per timestep ----------------
// n-major LDS tiles: a thread's 8 per-feature atomics land on 8 consecutive
// banks (f-major put all 8 on bank cc%32 -> 8-way serialization).
__global__ __launch_bounds__(256) void gcn_kernel(
        const float* __restrict__ x,      // [T, N, FIN]
        const int*   __restrict__ ei,     // [T, 2, E]
        const float* __restrict__ ew,     // [T, E]
        const float* __restrict__ Wg,     // [FIN, FOUT]
        const float* __restrict__ bg,     // [FOUT]
        float* __restrict__ feats)        // [T, HDIM]
{
    const int t   = blockIdx.x;
    const int tid = threadIdx.x;

    __shared__ float hs[N_NODES * FOUT];    // n-major: hs[n*8+f]
    __shared__ float outs[N_NODES * FOUT];  // n-major
    __shared__ float deg[N_NODES];
    __shared__ float Wsh[FIN * FOUT];
    __shared__ float bsh[FOUT];

    const float* xt   = x  + (size_t)t * N_NODES * FIN;
    const int*   rowp = ei + (size_t)t * 2 * E_EDGES;
    const int*   colp = rowp + E_EDGES;
    const float* wp   = ew + (size_t)t * E_EDGES;

    if (tid < FIN * FOUT) Wsh[tid] = Wg[tid];
    if (tid < FOUT)       bsh[tid] = bg[tid];
    for (int i = tid; i < N_NODES; i += 256) deg[i] = 1.0f;  // self-loop weight
    for (int i = tid; i < N_NODES * FOUT; i += 256) outs[i] = 0.0f;
    __syncthreads();

    // hs[n*8+f] = sum_k x[n][k] * W[k][f]
    for (int idx = tid; idx < N_NODES * FOUT; idx += 256) {
        const int n = idx >> 3;
        const int f = idx & 7;
        const float* xr = xt + n * FIN;
        float acc = 0.0f;
        #pragma unroll
        for (int k = 0; k < FIN; ++k) acc += xr[k] * Wsh[k * FOUT + f];
        hs[idx] = acc;
    }
    for (int e = tid; e < E_EDGES; e += 256) atomicAdd(&deg[colp[e]], wp[e]);
    __syncthreads();

    for (int i = tid; i < N_NODES; i += 256) deg[i] = 1.0f / sqrtf(deg[i]); // deg >= 1
    __syncthreads();

    // edge scatter: outs[col*8+f] += dinv[row]*w*dinv[col] * hs[row*8+f]
    for (int e = tid; e < E_EDGES; e += 256) {
        const int   r  = rowp[e];
        const int   cc = colp[e];
        const float coef = deg[r] * wp[e] * deg[cc];
        #pragma unroll
        for (int f = 0; f < FOUT; ++f)
            atomicAdd(&outs[cc * FOUT + f], coef * hs[r * FOUT + f]);
    }
    // self loops
    for (int n = tid; n < N_NODES; n += 256) {
        const float d2 = deg[n] * deg[n];
        #pragma unroll
        for (int f = 0; f < FOUT; ++f)
            atomicAdd(&outs[n * FOUT + f], d2 * hs[n * FOUT + f]);
    }
    __syncthreads();

    // feats[t][n*8+f] = relu(outs[n*8+f] + b[f]) — layouts match directly
    for (int idx = tid; idx < N_NODES * FOUT; idx += 256) {
        float v = outs[idx] + bsh[idx & 7];
        feats[(size_t)t * HDIM + idx] = v > 0.0f ? v : 0.0f;
    }
}

// ---------------- input-side GEMM: Xg[t][r] = b_ih[r]+b_hh[r] + feats[t].W_ih[r,:] ----------------
// 4 rows per wave, 4 waves per block -> 16 rows/block, 1024 blocks. W_ih read ONCE (nt).
__global__ __launch_bounds__(256) void wih_gemm(
        const float* __restrict__ feats,  // [T, HDIM]
        const float* __restrict__ Wih,    // [H4, HDIM]
        const float* __restrict__ b_ih,   // [H4]
        const float* __restrict__ b_hh,   // [H4]
        float* __restrict__ Xg)           // [T, H4]
{
    const int wave = threadIdx.x >> 6;
    const int lane = threadIdx.x & 63;
    const int r0   = blockIdx.x * 16 + wave * 4;

    const float4* W4 = (const float4*)Wih;
    const float4* F4 = (const float4*)feats;

    float acc[4][T_STEPS];
    #pragma unroll
    for (int a = 0; a < 4; ++a)
        #pragma unroll
        for (int t = 0; t < T_STEPS; ++t) acc[a][t] = 0.0f;

    #pragma unroll
    for (int c = 0; c < 16; ++c) {          // 16 chunks of 64 float4 = 4096 floats
        const int k4 = c * 64 + lane;
        float4 wv[4];
        #pragma unroll
        for (int a = 0; a < 4; ++a)
            wv[a] = ntload4(&W4[(size_t)(r0 + a) * (HDIM / 4) + k4]);
        #pragma unroll
        for (int t = 0; t < T_STEPS; ++t) {
            const float4 fv = F4[t * (HDIM / 4) + k4];
            #pragma unroll
            for (int a = 0; a < 4; ++a)
                acc[a][t] += wv[a].x * fv.x + wv[a].y * fv.y + wv[a].z * fv.z + wv[a].w * fv.w;
        }
    }

    #pragma unroll
    for (int a = 0; a < 4; ++a) {
        #pragma unroll
        for (int t = 0; t < T_STEPS; ++t) {
            float v = acc[a][t];
            #pragma unroll
            for (int off = 32; off > 0; off >>= 1) v += __shfl_xor(v, off, 64);
            if (lane == 0)
                Xg[t * H4 + r0 + a] = v + b_ih[r0 + a] + b_hh[r0 + a];
        }
    }
}

// ---------------- step 0: h=c=0 -> gates are Xg only (no GEMV, no init needed) ----------------
__global__ __launch_bounds__(256) void lstm_step0(
        const float* __restrict__ Xg0,    // [H4]
        float* __restrict__ h_out,        // [HDIM]
        float* __restrict__ c)            // [HDIM]
{
    const int j = blockIdx.x * 256 + threadIdx.x;
    const float gi = Xg0[j];
    const float gg = Xg0[2 * HDIM + j];
    const float go = Xg0[3 * HDIM + j];
    const float cj = sigmoidf_(gi) * tanhf(gg);   // f-gate * c0 == 0
    c[j] = cj;
    h_out[j] = sigmoidf_(go) * tanhf(cj);
}

// ---------------- step 1 fused: GEMV on fp32 weights (nt) + pack fp16 copy for later steps ----------------
__global__ __launch_bounds__(256) void lstm_step_cvt(
        const float* __restrict__ Xg_t,   // [H4]
        const float* __restrict__ Whh,    // [H4, HDIM] fp32
        uint4* __restrict__ Whh16,        // [H4 * HDIM/8] packed halves (out)
        const float* __restrict__ h_in,   // [HDIM]
        float* __restrict__ h_out,        // [HDIM]
        float* __restrict__ c)            // [HDIM] (in-place)
{
    const int j    = blockIdx.x;
    const int wave = threadIdx.x >> 6;
    const int lane = threadIdx.x & 63;
    const int r    = wave * HDIM + j;

    // prefetch tail operands off the critical path
    const float xg    = (lane == 0) ? Xg_t[r] : 0.0f;
    const float cprev = (threadIdx.x == 0) ? c[j] : 0.0f;

    const float4* Wr  = (const float4*)(Whh + (size_t)r * HDIM);
    uint4*        Wo  = Whh16 + (size_t)r * (HDIM / 8);
    const float4* h4  = (const float4*)h_in;

    float acc = 0.0f;
    #pragma unroll
    for (int it = 0; it < 8; ++it) {
        const int g = it * 64 + lane;          // group of 8 elements
        const float4 a  = ntload4(&Wr[2 * g]);
        const float4 b  = ntload4(&Wr[2 * g + 1]);
        const float4 ha = h4[2 * g];
        const float4 hb = h4[2 * g + 1];
        acc += a.x * ha.x + a.y * ha.y + a.z * ha.z + a.w * ha.w
             + b.x * hb.x + b.y * hb.y + b.z * hb.z + b.w * hb.w;
        union { uint4 u; __half2 h[4]; } pk;
        pk.h[0] = __floats2half2_rn(a.x, a.y);
        pk.h[1] = __floats2half2_rn(a.z, a.w);
        pk.h[2] = __floats2half2_rn(b.x, b.y);
        pk.h[3] = __floats2half2_rn(b.z, b.w);
        Wo[g] = pk.u;
    }
    #pragma unroll
    for (int off = 32; off > 0; off >>= 1) acc += __shfl_xor(acc, off, 64);

    __shared__ float gate[4];
    if (lane == 0) gate[wave] = acc + xg;
    __syncthreads();

    if (threadIdx.x == 0) {
        const float gi = gate[0], gf = gate[1], gg = gate[2], go = gate[3];
        const float cj = sigmoidf_(gf) * cprev + sigmoidf_(gi) * tanhf(gg);
        const float hj = sigmoidf_(go) * tanhf(cj);
        c[j] = cj;
        h_out[j] = hj;
    }
}

// ---------------- recurrent step, fp16 weights: one block per hidden unit j ----------------
__global__ __launch_bounds__(256) void lstm_step_f16(
        const float* __restrict__ Xg_t,   // [H4]
        const uint4* __restrict__ Whh16,  // [H4 * HDIM/8] packed halves
        const float* __restrict__ h_in,   // [HDIM]
        float* __restrict__ h_out,        // [HDIM]
        float* __restrict__ c,            // [HDIM] (in-place)
        float* __restrict__ final_out)    // nullptr or [2*HDIM]: c then h
{
    const int j    = blockIdx.x;
    const int wave = threadIdx.x >> 6;
    const int lane = threadIdx.x & 63;
    const int r    = wave * HDIM + j;

    const float xg    = (lane == 0) ? Xg_t[r] : 0.0f;
    const float cprev = (threadIdx.x == 0) ? c[j] : 0.0f;

    const uint4*  Wr = Whh16 + (size_t)r * (HDIM / 8);
    const float4* h4 = (const float4*)h_in;

    float acc = 0.0f;
    #pragma unroll
    for (int it = 0; it < 8; ++it) {
        const int g = it * 64 + lane;          // group of 8 elements
        uint4 wraw = Wr[g];
        const __half2* wh = (const __half2*)&wraw;
        const float4 ha = h4[2 * g];
        const float4 hb = h4[2 * g + 1];
        const float2 w0 = __half22float2(wh[0]);
        const float2 w1 = __half22float2(wh[1]);
        const float2 w2 = __half22float2(wh[2]);
        const float2 w3 = __half22float2(wh[3]);
        acc += w0.x * ha.x + w0.y * ha.y + w1.x * ha.z + w1.y * ha.w
             + w2.x * hb.x + w2.y * hb.y + w3.x * hb.z + w3.y * hb.w;
    }
    #pragma unroll
    for (int off = 32; off > 0; off >>= 1) acc += __shfl_xor(acc, off, 64);

    __shared__ float gate[4];
    if (lane == 0) gate[wave] = acc + xg;
    __syncthreads();

    if (threadIdx.x == 0) {
        const float gi = gate[0], gf = gate[1], gg = gate[2], go = gate[3];
        const float cj = sigmoidf_(gf) * cprev + sigmoidf_(gi) * tanhf(gg);
        const float hj = sigmoidf_(go) * tanhf(cj);
        c[j] = cj;
        h_out[j] = hj;
        if (final_out) { final_out[j] = cj; final_out[HDIM + j] = hj; }
    }
}

// ---------------- recurrent step, fp32 weights (fallback if ws too small) ----------------
__global__ __launch_bounds__(256) void lstm_step_f32(
        const float* __restrict__ Xg_t,
        const float* __restrict__ Whh,    // [H4, HDIM]
        const float* __restrict__ h_in,
        float* __restrict__ h_out,
        float* __restrict__ c,
        float* __restrict__ final_out)
{
    const int j    = blockIdx.x;
    const int wave = threadIdx.x >> 6;
    const int lane = threadIdx.x & 63;
    const int r    = wave * HDIM + j;

    const float xg    = (lane == 0) ? Xg_t[r] : 0.0f;
    const float cprev = (threadIdx.x == 0) ? c[j] : 0.0f;

    const float4* Wr = (const float4*)(Whh + (size_t)r * HDIM);
    const float4* h4 = (const float4*)h_in;

    float acc = 0.0f;
    #pragma unroll
    for (int it = 0; it < 16; ++it) {
        const int k4 = it * 64 + lane;
        const float4 w = Wr[k4];
        const float4 h = h4[k4];
        acc += w.x * h.x + w.y * h.y + w.z * h.z + w.w * h.w;
    }
    #pragma unroll
    for (int off = 32; off > 0; off >>= 1) acc += __shfl_xor(acc, off, 64);

    __shared__ float gate[4];
    if (lane == 0) gate[wave] = acc + xg;
    __syncthreads();

    if (threadIdx.x == 0) {
        const float gi = gate[0], gf = gate[1], gg = gate[2], go = gate[3];
        const float cj = sigmoidf_(gf) * cprev + sigmoidf_(gi) * tanhf(gg);
        const float hj = sigmoidf_(go) * tanhf(cj);
        c[j] = cj;
        h_out[j] = hj;
        if (final_out) { final_out[j] = cj; final_out[HDIM + j] = hj; }
    }
}

extern "C" void kernel_launch(void* const* d_in, const int* in_sizes, int n_in,
                              void* d_out, int out_size, void* d_ws, size_t ws_size,
                              hipStream_t stream) {
    const float* x    = (const float*)d_in[0];
    const int*   ei   = (const int*)  d_in[1];
    const float* ew   = (const float*)d_in[2];
    const float* Wg   = (const float*)d_in[3];
    const float* bg   = (const float*)d_in[4];
    const float* Wih  = (const float*)d_in[5];
    const float* Whh  = (const float*)d_in[6];
    const float* b_ih = (const float*)d_in[7];
    const float* b_hh = (const float*)d_in[8];
    float* out = (float*)d_out;

    const size_t fp16_bytes  = (size_t)H4 * HDIM * sizeof(__half);        // 128 MiB
    const size_t float_elems = (size_t)T_STEPS * HDIM + (size_t)T_STEPS * H4 + 3 * HDIM;
    const bool   use_fp16    = ws_size >= fp16_bytes + float_elems * sizeof(float);

    char*  base  = (char*)d_ws;
    uint4* Whh16 = (uint4*)base;                                          // fp16 copy (or unused)
    float* fbase = use_fp16 ? (float*)(base + fp16_bytes) : (float*)base;
    float* feats = fbase;                       // T*HDIM
    float* Xg    = feats + T_STEPS * HDIM;      // T*H4
    float* hA    = Xg + T_STEPS * H4;           // HDIM
    float* hB    = hA + HDIM;                   // HDIM
    float* c     = hB + HDIM;                   // HDIM

    gcn_kernel<<<T_STEPS, 256, 0, stream>>>(x, ei, ew, Wg, bg, feats);
    wih_gemm<<<H4 / 16, 256, 0, stream>>>(feats, Wih, b_ih, b_hh, Xg);

    // step 0: h0 = c0 = 0 -> no GEMV (also initializes c, h without any init kernel)
    lstm_step0<<<HDIM / 256, 256, 0, stream>>>(Xg, hA, c);

    float* hin = hA;
    float* hout = hB;
    if (use_fp16) {
        // step 1: GEMV on fp32 weights (nt), fused fp16 pack (read 256 MiB, write 128 MiB)
        lstm_step_cvt<<<HDIM, 256, 0, stream>>>(Xg + (size_t)1 * H4, Whh, Whh16, hin, hout, c);
        { float* tmp = hin; hin = hout; hout = tmp; }
        // steps 2..11: fp16 weights (128 MiB, Infinity-Cache-resident)
        for (int t = 2; t < T_STEPS; ++t) {
            float* fout = (t == T_STEPS - 1) ? out : nullptr;
            lstm_step_f16<<<HDIM, 256, 0, stream>>>(Xg + (size_t)t * H4, Whh16, hin, hout, c, fout);
            float* tmp = hin; hin = hout; hout = tmp;
        }
    } else {
        for (int t = 1; t < T_STEPS; ++t) {
            float* fout = (t == T_STEPS - 1) ? out : nullptr;
            lstm_step_f32<<<HDIM, 256, 0, stream>>>(Xg + (size_t)t * H4, Whh, hin, hout, c, fout);
            float* tmp = hin; hin = hout; hout = tmp;
        }
    }
}

// Round 8
// 993.859 us; speedup vs baseline: 1.8077x; 1.8077x over previous
//
#include <hip/hip_runtime.h>
#include <hip/hip_fp16.h>
#include <math.h>

#define T_STEPS 12
#define N_NODES 512
#define FIN 32
#define FOUT 8
#define E_EDGES 16384
#define HDIM 4096    // N_NODES * FOUT
#define H4 16384     // 4 * HDIM

__device__ __forceinline__ float sigmoidf_(float x) { return 1.0f / (1.0f + __expf(-x)); }

// non-temporal 16B load: __builtin_nontemporal_load requires a scalar/Clang-vector
// type -- HIP's float4 is a class, so go through an ext_vector_type.
typedef float floatx4 __attribute__((ext_vector_type(4)));
__device__ __forceinline__ float4 ntload4(const float4* p) {
    floatx4 v = __builtin_nontemporal_load((const floatx4*)p);
    return make_float4(v.x, v.y, v.z, v.w);
}

// ---------------- GCN: one block per timestep ----------------
__global__ __launch_bounds__(256) void gcn_kernel(
        const float* __restrict__ x,      // [T, N, FIN]
        const int*   __restrict__ ei,     // [T, 2, E]
        const float* __restrict__ ew,     // [T, E]
        const float* __restrict__ Wg,     // [FIN, FOUT]
        const float* __restrict__ bg,     // [FOUT]
        float* __restrict__ feats)        // [T, HDIM]
{
    const int t   = blockIdx.x;
    const int tid = threadIdx.x;

    __shared__ float hs[N_NODES * FOUT];    // n-major: hs[n*8+f]
    __shared__ float outs[N_NODES * FOUT];  // n-major
    __shared__ float deg[N_NODES];
    __shared__ float Wsh[FIN * FOUT];
    __shared__ float bsh[FOUT];

    const float* xt   = x  + (size_t)t * N_NODES * FIN;
    const int*   rowp = ei + (size_t)t * 2 * E_EDGES;
    const int*   colp = rowp + E_EDGES;
    const float* wp   = ew + (size_t)t * E_EDGES;

    if (tid < FIN * FOUT) Wsh[tid] = Wg[tid];
    if (tid < FOUT)       bsh[tid] = bg[tid];
    for (int i = tid; i < N_NODES; i += 256) deg[i] = 1.0f;  // self-loop weight
    for (int i = tid; i < N_NODES * FOUT; i += 256) outs[i] = 0.0f;
    __syncthreads();

    // hs[n*8+f] = sum_k x[n][k] * W[k][f]
    for (int idx = tid; idx < N_NODES * FOUT; idx += 256) {
        const int n = idx >> 3;
        const int f = idx & 7;
        const float* xr = xt + n * FIN;
        float acc = 0.0f;
        #pragma unroll
        for (int k = 0; k < FIN; ++k) acc += xr[k] * Wsh[k * FOUT + f];
        hs[idx] = acc;
    }
    for (int e = tid; e < E_EDGES; e += 256) atomicAdd(&deg[colp[e]], wp[e]);
    __syncthreads();

    for (int i = tid; i < N_NODES; i += 256) deg[i] = 1.0f / sqrtf(deg[i]); // deg >= 1
    __syncthreads();

    // edge scatter: outs[col*8+f] += dinv[row]*w*dinv[col] * hs[row*8+f]
    for (int e = tid; e < E_EDGES; e += 256) {
        const int   r  = rowp[e];
        const int   cc = colp[e];
        const float coef = deg[r] * wp[e] * deg[cc];
        #pragma unroll
        for (int f = 0; f < FOUT; ++f)
            atomicAdd(&outs[cc * FOUT + f], coef * hs[r * FOUT + f]);
    }
    // self loops
    for (int n = tid; n < N_NODES; n += 256) {
        const float d2 = deg[n] * deg[n];
        #pragma unroll
        for (int f = 0; f < FOUT; ++f)
            atomicAdd(&outs[n * FOUT + f], d2 * hs[n * FOUT + f]);
    }
    __syncthreads();

    // feats[t][n*8+f] = relu(outs[n*8+f] + b[f])
    for (int idx = tid; idx < N_NODES * FOUT; idx += 256) {
        float v = outs[idx] + bsh[idx & 7];
        feats[(size_t)t * HDIM + idx] = v > 0.0f ? v : 0.0f;
    }
}

// ---------------- input-side GEMM: Xg[t][r] = b_ih[r]+b_hh[r] + feats[t].W_ih[r,:] ----------------
// 2 rows per wave (24 accumulators -> no spill), 4 waves/block = 8 rows/block,
// 2048 blocks (8/CU, full occupancy). Chunk loop NOT unrolled: the previous
// full unroll hoisted 64 loads, forced VGPR=256 and 555 MB of scratch spills.
__global__ __launch_bounds__(256) void wih_gemm(
        const float* __restrict__ feats,  // [T, HDIM]
        const float* __restrict__ Wih,    // [H4, HDIM]
        const float* __restrict__ b_ih,   // [H4]
        const float* __restrict__ b_hh,   // [H4]
        float* __restrict__ Xg)           // [T, H4]
{
    const int wave = threadIdx.x >> 6;
    const int lane = threadIdx.x & 63;
    const int r0   = blockIdx.x * 8 + wave * 2;

    const float4* W4 = (const float4*)Wih;
    const float4* F4 = (const float4*)feats;

    float acc0[T_STEPS], acc1[T_STEPS];
    #pragma unroll
    for (int t = 0; t < T_STEPS; ++t) { acc0[t] = 0.0f; acc1[t] = 0.0f; }

    #pragma unroll 1
    for (int ch = 0; ch < 16; ++ch) {       // 16 chunks of 64 float4 = 4096 floats
        const int k4 = ch * 64 + lane;
        const float4 w0 = ntload4(&W4[(size_t)r0 * (HDIM / 4) + k4]);
        const float4 w1 = ntload4(&W4[(size_t)(r0 + 1) * (HDIM / 4) + k4]);
        #pragma unroll
        for (int t = 0; t < T_STEPS; ++t) {
            const float4 fv = F4[t * (HDIM / 4) + k4];
            acc0[t] += w0.x * fv.x + w0.y * fv.y + w0.z * fv.z + w0.w * fv.w;
            acc1[t] += w1.x * fv.x + w1.y * fv.y + w1.z * fv.z + w1.w * fv.w;
        }
    }

    const float bias0 = b_ih[r0] + b_hh[r0];
    const float bias1 = b_ih[r0 + 1] + b_hh[r0 + 1];

    #pragma unroll
    for (int t = 0; t < T_STEPS; ++t) {
        float v0 = acc0[t], v1 = acc1[t];
        #pragma unroll
        for (int off = 32; off > 0; off >>= 1) {
            v0 += __shfl_xor(v0, off, 64);
            v1 += __shfl_xor(v1, off, 64);
        }
        if (lane == 0) {
            Xg[t * H4 + r0]     = v0 + bias0;
            Xg[t * H4 + r0 + 1] = v1 + bias1;
        }
    }
}

// ---------------- step 0: h=c=0 -> gates are Xg only (no GEMV, no init needed) ----------------
__global__ __launch_bounds__(256) void lstm_step0(
        const float* __restrict__ Xg0,    // [H4]
        float* __restrict__ h_out,        // [HDIM]
        float* __restrict__ c)            // [HDIM]
{
    const int j = blockIdx.x * 256 + threadIdx.x;
    const float gi = Xg0[j];
    const float gg = Xg0[2 * HDIM + j];
    const float go = Xg0[3 * HDIM + j];
    const float cj = sigmoidf_(gi) * tanhf(gg);   // f-gate * c0 == 0
    c[j] = cj;
    h_out[j] = sigmoidf_(go) * tanhf(cj);
}

// ---------------- step 1 fused: GEMV on fp32 weights (nt) + pack fp16 copy for later steps ----------------
__global__ __launch_bounds__(256) void lstm_step_cvt(
        const float* __restrict__ Xg_t,   // [H4]
        const float* __restrict__ Whh,    // [H4, HDIM] fp32
        uint4* __restrict__ Whh16,        // [H4 * HDIM/8] packed halves (out)
        const float* __restrict__ h_in,   // [HDIM]
        float* __restrict__ h_out,        // [HDIM]
        float* __restrict__ c)            // [HDIM] (in-place)
{
    const int j    = blockIdx.x;
    const int wave = threadIdx.x >> 6;
    const int lane = threadIdx.x & 63;
    const int r    = wave * HDIM + j;

    // prefetch tail operands off the critical path
    const float xg    = (lane == 0) ? Xg_t[r] : 0.0f;
    const float cprev = (threadIdx.x == 0) ? c[j] : 0.0f;

    const float4* Wr  = (const float4*)(Whh + (size_t)r * HDIM);
    uint4*        Wo  = Whh16 + (size_t)r * (HDIM / 8);
    const float4* h4  = (const float4*)h_in;

    float acc = 0.0f;
    #pragma unroll
    for (int it = 0; it < 8; ++it) {
        const int g = it * 64 + lane;          // group of 8 elements
        const float4 a  = ntload4(&Wr[2 * g]);
        const float4 b  = ntload4(&Wr[2 * g + 1]);
        const float4 ha = h4[2 * g];
        const float4 hb = h4[2 * g + 1];
        acc += a.x * ha.x + a.y * ha.y + a.z * ha.z + a.w * ha.w
             + b.x * hb.x + b.y * hb.y + b.z * hb.z + b.w * hb.w;
        union { uint4 u; __half2 h[4]; } pk;
        pk.h[0] = __floats2half2_rn(a.x, a.y);
        pk.h[1] = __floats2half2_rn(a.z, a.w);
        pk.h[2] = __floats2half2_rn(b.x, b.y);
        pk.h[3] = __floats2half2_rn(b.z, b.w);
        Wo[g] = pk.u;
    }
    #pragma unroll
    for (int off = 32; off > 0; off >>= 1) acc += __shfl_xor(acc, off, 64);

    __shared__ float gate[4];
    if (lane == 0) gate[wave] = acc + xg;
    __syncthreads();

    if (threadIdx.x == 0) {
        const float gi = gate[0], gf = gate[1], gg = gate[2], go = gate[3];
        const float cj = sigmoidf_(gf) * cprev + sigmoidf_(gi) * tanhf(gg);
        const float hj = sigmoidf_(go) * tanhf(cj);
        c[j] = cj;
        h_out[j] = hj;
    }
}

// ---------------- recurrent step, fp16 weights: one block per hidden unit j ----------------
__global__ __launch_bounds__(256) void lstm_step_f16(
        const float* __restrict__ Xg_t,   // [H4]
        const uint4* __restrict__ Whh16,  // [H4 * HDIM/8] packed halves
        const float* __restrict__ h_in,   // [HDIM]
        float* __restrict__ h_out,        // [HDIM]
        float* __restrict__ c,            // [HDIM] (in-place)
        float* __restrict__ final_out)    // nullptr or [2*HDIM]: c then h
{
    const int j    = blockIdx.x;
    const int wave = threadIdx.x >> 6;
    const int lane = threadIdx.x & 63;
    const int r    = wave * HDIM + j;

    const float xg    = (lane == 0) ? Xg_t[r] : 0.0f;
    const float cprev = (threadIdx.x == 0) ? c[j] : 0.0f;

    const uint4*  Wr = Whh16 + (size_t)r * (HDIM / 8);
    const float4* h4 = (const float4*)h_in;

    float acc = 0.0f;
    #pragma unroll
    for (int it = 0; it < 8; ++it) {
        const int g = it * 64 + lane;          // group of 8 elements
        uint4 wraw = Wr[g];
        const __half2* wh = (const __half2*)&wraw;
        const float4 ha = h4[2 * g];
        const float4 hb = h4[2 * g + 1];
        const float2 w0 = __half22float2(wh[0]);
        const float2 w1 = __half22float2(wh[1]);
        const float2 w2 = __half22float2(wh[2]);
        const float2 w3 = __half22float2(wh[3]);
        acc += w0.x * ha.x + w0.y * ha.y + w1.x * ha.z + w1.y * ha.w
             + w2.x * hb.x + w2.y * hb.y + w3.x * hb.z + w3.y * hb.w;
    }
    #pragma unroll
    for (int off = 32; off > 0; off >>= 1) acc += __shfl_xor(acc, off, 64);

    __shared__ float gate[4];
    if (lane == 0) gate[wave] = acc + xg;
    __syncthreads();

    if (threadIdx.x == 0) {
        const float gi = gate[0], gf = gate[1], gg = gate[2], go = gate[3];
        const float cj = sigmoidf_(gf) * cprev + sigmoidf_(gi) * tanhf(gg);
        const float hj = sigmoidf_(go) * tanhf(cj);
        c[j] = cj;
        h_out[j] = hj;
        if (final_out) { final_out[j] = cj; final_out[HDIM + j] = hj; }
    }
}

// ---------------- recurrent step, fp32 weights (fallback if ws too small) ----------------
__global__ __launch_bounds__(256) void lstm_step_f32(
        const float* __restrict__ Xg_t,
        const float* __restrict__ Whh,    // [H4, HDIM]
        const float* __restrict__ h_in,
        float* __restrict__ h_out,
        float* __restrict__ c,
        float* __restrict__ final_out)
{
    const int j    = blockIdx.x;
    const int wave = threadIdx.x >> 6;
    const int lane = threadIdx.x & 63;
    const int r    = wave * HDIM + j;

    const float xg    = (lane == 0) ? Xg_t[r] : 0.0f;
    const float cprev = (threadIdx.x == 0) ? c[j] : 0.0f;

    const float4* Wr = (const float4*)(Whh + (size_t)r * HDIM);
    const float4* h4 = (const float4*)h_in;

    float acc = 0.0f;
    #pragma unroll
    for (int it = 0; it < 16; ++it) {
        const int k4 = it * 64 + lane;
        const float4 w = Wr[k4];
        const float4 h = h4[k4];
        acc += w.x * h.x + w.y * h.y + w.z * h.z + w.w * h.w;
    }
    #pragma unroll
    for (int off = 32; off > 0; off >>= 1) acc += __shfl_xor(acc, off, 64);

    __shared__ float gate[4];
    if (lane == 0) gate[wave] = acc + xg;
    __syncthreads();

    if (threadIdx.x == 0) {
        const float gi = gate[0], gf = gate[1], gg = gate[2], go = gate[3];
        const float cj = sigmoidf_(gf) * cprev + sigmoidf_(gi) * tanhf(gg);
        const float hj = sigmoidf_(go) * tanhf(cj);
        c[j] = cj;
        h_out[j] = hj;
        if (final_out) { final_out[j] = cj; final_out[HDIM + j] = hj; }
    }
}

extern "C" void kernel_launch(void* const* d_in, const int* in_sizes, int n_in,
                              void* d_out, int out_size, void* d_ws, size_t ws_size,
                              hipStream_t stream) {
    const float* x    = (const float*)d_in[0];
    const int*   ei   = (const int*)  d_in[1];
    const float* ew   = (const float*)d_in[2];
    const float* Wg   = (const float*)d_in[3];
    const float* bg   = (const float*)d_in[4];
    const float* Wih  = (const float*)d_in[5];
    const float* Whh  = (const float*)d_in[6];
    const float* b_ih = (const float*)d_in[7];
    const float* b_hh = (const float*)d_in[8];
    float* out = (float*)d_out;

    const size_t fp16_bytes  = (size_t)H4 * HDIM * sizeof(__half);        // 128 MiB
    const size_t float_elems = (size_t)T_STEPS * HDIM + (size_t)T_STEPS * H4 + 3 * HDIM;
    const bool   use_fp16    = ws_size >= fp16_bytes + float_elems * sizeof(float);

    char*  base  = (char*)d_ws;
    uint4* Whh16 = (uint4*)base;                                          // fp16 copy (or unused)
    float* fbase = use_fp16 ? (float*)(base + fp16_bytes) : (float*)base;
    float* feats = fbase;                       // T*HDIM
    float* Xg    = feats + T_STEPS * HDIM;      // T*H4
    float* hA    = Xg + T_STEPS * H4;           // HDIM
    float* hB    = hA + HDIM;                   // HDIM
    float* c     = hB + HDIM;                   // HDIM

    gcn_kernel<<<T_STEPS, 256, 0, stream>>>(x, ei, ew, Wg, bg, feats);
    wih_gemm<<<H4 / 8, 256, 0, stream>>>(feats, Wih, b_ih, b_hh, Xg);

    // step 0: h0 = c0 = 0 -> no GEMV (also initializes c, h without any init kernel)
    lstm_step0<<<HDIM / 256, 256, 0, stream>>>(Xg, hA, c);

    float* hin = hA;
    float* hout = hB;
    if (use_fp16) {
        // step 1: GEMV on fp32 weights (nt), fused fp16 pack (read 256 MiB, write 128 MiB)
        lstm_step_cvt<<<HDIM, 256, 0, stream>>>(Xg + (size_t)1 * H4, Whh, Whh16, hin, hout, c);
        { float* tmp = hin; hin = hout; hout = tmp; }
        // steps 2..11: fp16 weights (128 MiB, Infinity-Cache-resident)
        for (int t = 2; t < T_STEPS; ++t) {
            float* fout = (t == T_STEPS - 1) ? out : nullptr;
            lstm_step_f16<<<HDIM, 256, 0, stream>>>(Xg + (size_t)t * H4, Whh16, hin, hout, c, fout);
            float* tmp = hin; hin = hout; hout = tmp;
        }
    } else {
        for (int t = 1; t < T_STEPS; ++t) {
            float* fout = (t == T_STEPS - 1) ? out : nullptr;
            lstm_step_f32<<<HDIM, 256, 0, stream>>>(Xg + (size_t)t * H4, Whh, hin, hout, c, fout);
            float* tmp = hin; hin = hout; hout = tmp;
        }
    }
}

// Round 13
// 813.804 us; speedup vs baseline: 2.2076x; 1.2213x over previous
//
#include <hip/hip_runtime.h>
#include <hip/hip_fp16.h>
#include <math.h>

#define T_STEPS 12
#define N_NODES 512
#define FIN 32
#define FOUT 8
#define E_EDGES 16384
#define HDIM 4096    // N_NODES * FOUT
#define H4 16384     // 4 * HDIM
#define KSPLIT 16    // blocks per timestep for edge processing
#define EPB (E_EDGES / KSPLIT)   // 1024 edges per block

__device__ __forceinline__ float sigmoidf_(float x) { return 1.0f / (1.0f + __expf(-x)); }

// non-temporal 16B load (single-use streams; float4 is a class -> ext_vector_type)
typedef float floatx4 __attribute__((ext_vector_type(4)));
__device__ __forceinline__ float4 ntload4(const float4* p) {
    floatx4 v = __builtin_nontemporal_load((const floatx4*)p);
    return make_float4(v.x, v.y, v.z, v.w);
}

// ---------------- GCN kernel A: hs = x@W, zero deg/acc ----------------
__global__ __launch_bounds__(256) void gcn_hs_init(
        const float* __restrict__ x,      // [T, N, FIN]
        const float* __restrict__ Wg,     // [FIN, FOUT]
        float* __restrict__ hs_g,         // [T, HDIM]
        float* __restrict__ deg_g,        // [T, N] (edge-weight sums, excl. self loop)
        float* __restrict__ acc_g)        // [T, HDIM]
{
    const int idx = blockIdx.x * 256 + threadIdx.x;   // 0 .. T*HDIM
    const int t  = idx >> 12;
    const int nf = idx & (HDIM - 1);
    const int n  = nf >> 3;
    const int f  = nf & 7;
    const float* xr = x + ((size_t)t * N_NODES + n) * FIN;
    float acc = 0.0f;
    #pragma unroll
    for (int k = 0; k < FIN; ++k) acc += xr[k] * Wg[k * FOUT + f];
    hs_g[idx]  = acc;
    acc_g[idx] = 0.0f;
    if (f == 0) deg_g[t * N_NODES + n] = 0.0f;
}

// ---------------- GCN kernel B: deg_g += edge weights (global atomics) ----------------
__global__ __launch_bounds__(256) void gcn_deg(
        const int*   __restrict__ ei,     // [T, 2, E]
        const float* __restrict__ ew,     // [T, E]
        float* __restrict__ deg_g)        // [T, N]
{
    const int t = blockIdx.x / KSPLIT;
    const int s = blockIdx.x % KSPLIT;
    const int* colp = ei + (size_t)t * 2 * E_EDGES + E_EDGES;
    const float* wp = ew + (size_t)t * E_EDGES;
    const int e0 = s * EPB;
    for (int e = e0 + threadIdx.x; e < e0 + EPB; e += 256)
        atomicAdd(&deg_g[t * N_NODES + colp[e]], wp[e]);
}

// ---------------- GCN kernel C: edge scatter (LDS partial -> global atomics) ----------------
__global__ __launch_bounds__(256) void gcn_scatter(
        const int*   __restrict__ ei,
        const float* __restrict__ ew,
        const float* __restrict__ hs_g,   // [T, HDIM]
        const float* __restrict__ deg_g,  // [T, N]
        float* __restrict__ acc_g)        // [T, HDIM]
{
    const int t = blockIdx.x / KSPLIT;
    const int s = blockIdx.x % KSPLIT;

    __shared__ float outs[HDIM];          // n-major partial [n*8+f]
    for (int i = threadIdx.x; i < HDIM; i += 256) outs[i] = 0.0f;
    __syncthreads();

    const int*   rowp = ei + (size_t)t * 2 * E_EDGES;
    const int*   colp = rowp + E_EDGES;
    const float* wp   = ew + (size_t)t * E_EDGES;
    const float* hs   = hs_g + (size_t)t * HDIM;
    const float* dg   = deg_g + t * N_NODES;

    const int e0 = s * EPB;
    for (int e = e0 + threadIdx.x; e < e0 + EPB; e += 256) {
        const int   r  = rowp[e];
        const int   cc = colp[e];
        // exact form matching the reference's dinv[row]*w*dinv[col]
        const float coef = wp[e] / sqrtf((1.0f + dg[r]) * (1.0f + dg[cc]));
        #pragma unroll
        for (int f = 0; f < FOUT; ++f)
            atomicAdd(&outs[cc * FOUT + f], coef * hs[r * FOUT + f]);
    }
    __syncthreads();

    float* acc = acc_g + (size_t)t * HDIM;
    for (int i = threadIdx.x; i < HDIM; i += 256)
        atomicAdd(&acc[i], outs[i]);
}

// ---------------- GCN kernel D: finalize (self-loop + bias + relu) ----------------
__global__ __launch_bounds__(256) void gcn_final(
        const float* __restrict__ acc_g,
        const float* __restrict__ hs_g,
        const float* __restrict__ deg_g,
        const float* __restrict__ bg,
        float* __restrict__ feats)        // [T, HDIM]
{
    const int idx = blockIdx.x * 256 + threadIdx.x;
    const int t  = idx >> 12;
    const int nf = idx & (HDIM - 1);
    const int n  = nf >> 3;
    const float dinv2 = 1.0f / (1.0f + deg_g[t * N_NODES + n]);  // dinv^2 = 1/deg
    const float v = acc_g[idx] + dinv2 * hs_g[idx] + bg[nf & 7];
    feats[idx] = v > 0.0f ? v : 0.0f;
}

// ---------------- input-side GEMM: Xg[t][r] = b_ih[r]+b_hh[r] + feats[t].W_ih[r,:] ----------------
// 2 rows per wave (no spill), 8 rows/block, 2048 blocks.
__global__ __launch_bounds__(256) void wih_gemm(
        const float* __restrict__ feats,  // [T, HDIM]
        const float* __restrict__ Wih,    // [H4, HDIM]
        const float* __restrict__ b_ih,   // [H4]
        const float* __restrict__ b_hh,   // [H4]
        float* __restrict__ Xg)           // [T, H4]
{
    const int wave = threadIdx.x >> 6;
    const int lane = threadIdx.x & 63;
    const int r0   = blockIdx.x * 8 + wave * 2;

    const float4* W4 = (const float4*)Wih;
    const float4* F4 = (const float4*)feats;

    float acc0[T_STEPS], acc1[T_STEPS];
    #pragma unroll
    for (int t = 0; t < T_STEPS; ++t) { acc0[t] = 0.0f; acc1[t] = 0.0f; }

    #pragma unroll 1
    for (int ch = 0; ch < 16; ++ch) {       // 16 chunks of 64 float4 = 4096 floats
        const int k4 = ch * 64 + lane;
        const float4 w0 = ntload4(&W4[(size_t)r0 * (HDIM / 4) + k4]);
        const float4 w1 = ntload4(&W4[(size_t)(r0 + 1) * (HDIM / 4) + k4]);
        #pragma unroll
        for (int t = 0; t < T_STEPS; ++t) {
            const float4 fv = F4[t * (HDIM / 4) + k4];
            acc0[t] += w0.x * fv.x + w0.y * fv.y + w0.z * fv.z + w0.w * fv.w;
            acc1[t] += w1.x * fv.x + w1.y * fv.y + w1.z * fv.z + w1.w * fv.w;
        }
    }

    const float bias0 = b_ih[r0] + b_hh[r0];
    const float bias1 = b_ih[r0 + 1] + b_hh[r0 + 1];

    #pragma unroll
    for (int t = 0; t < T_STEPS; ++t) {
        float v0 = acc0[t], v1 = acc1[t];
        #pragma unroll
        for (int off = 32; off > 0; off >>= 1) {
            v0 += __shfl_xor(v0, off, 64);
            v1 += __shfl_xor(v1, off, 64);
        }
        if (lane == 0) {
            Xg[t * H4 + r0]     = v0 + bias0;
            Xg[t * H4 + r0 + 1] = v1 + bias1;
        }
    }
}

// ---------------- step 0: h=c=0 -> gates are Xg only ----------------
__global__ __launch_bounds__(256) void lstm_step0(
        const float* __restrict__ Xg0,    // [H4]
        float* __restrict__ h_out,        // [HDIM]
        float* __restrict__ c)            // [HDIM]
{
    const int j = blockIdx.x * 256 + threadIdx.x;
    const float gi = Xg0[j];
    const float gg = Xg0[2 * HDIM + j];
    const float go = Xg0[3 * HDIM + j];
    const float cj = sigmoidf_(gi) * tanhf(gg);   // f-gate * c0 == 0
    c[j] = cj;
    h_out[j] = sigmoidf_(go) * tanhf(cj);
}

// ---------------- step 1 fused: GEMV on fp32 weights (nt) + pack fp16 copy ----------------
__global__ __launch_bounds__(256) void lstm_step_cvt(
        const float* __restrict__ Xg_t,   // [H4]
        const float* __restrict__ Whh,    // [H4, HDIM] fp32
        uint4* __restrict__ Whh16,        // [H4 * HDIM/8] packed halves (out)
        const float* __restrict__ h_in,   // [HDIM]
        float* __restrict__ h_out,        // [HDIM]
        float* __restrict__ c)            // [HDIM] (in-place)
{
    const int j    = blockIdx.x;
    const int wave = threadIdx.x >> 6;
    const int lane = threadIdx.x & 63;
    const int r    = wave * HDIM + j;

    const float xg    = (lane == 0) ? Xg_t[r] : 0.0f;
    const float cprev = (threadIdx.x == 0) ? c[j] : 0.0f;

    const float4* Wr  = (const float4*)(Whh + (size_t)r * HDIM);
    uint4*        Wo  = Whh16 + (size_t)r * (HDIM / 8);
    const float4* h4  = (const float4*)h_in;

    float acc = 0.0f;
    #pragma unroll
    for (int it = 0; it < 8; ++it) {
        const int g = it * 64 + lane;          // group of 8 elements
        const float4 a  = ntload4(&Wr[2 * g]);
        const float4 b  = ntload4(&Wr[2 * g + 1]);
        const float4 ha = h4[2 * g];
        const float4 hb = h4[2 * g + 1];
        acc += a.x * ha.x + a.y * ha.y + a.z * ha.z + a.w * ha.w
             + b.x * hb.x + b.y * hb.y + b.z * hb.z + b.w * hb.w;
        union { uint4 u; __half2 h[4]; } pk;
        pk.h[0] = __floats2half2_rn(a.x, a.y);
        pk.h[1] = __floats2half2_rn(a.z, a.w);
        pk.h[2] = __floats2half2_rn(b.x, b.y);
        pk.h[3] = __floats2half2_rn(b.z, b.w);
        Wo[g] = pk.u;
    }
    #pragma unroll
    for (int off = 32; off > 0; off >>= 1) acc += __shfl_xor(acc, off, 64);

    __shared__ float gate[4];
    if (lane == 0) gate[wave] = acc + xg;
    __syncthreads();

    if (threadIdx.x == 0) {
        const float gi = gate[0], gf = gate[1], gg = gate[2], go = gate[3];
        const float cj = sigmoidf_(gf) * cprev + sigmoidf_(gi) * tanhf(gg);
        const float hj = sigmoidf_(go) * tanhf(cj);
        c[j] = cj;
        h_out[j] = hj;
    }
}

// ---------------- recurrent step, fp16 weights ----------------
__global__ __launch_bounds__(256) void lstm_step_f16(
        const float* __restrict__ Xg_t,   // [H4]
        const uint4* __restrict__ Whh16,  // [H4 * HDIM/8] packed halves
        const float* __restrict__ h_in,   // [HDIM]
        float* __restrict__ h_out,        // [HDIM]
        float* __restrict__ c,            // [HDIM] (in-place)
        float* __restrict__ final_out)    // nullptr or [2*HDIM]: c then h
{
    const int j    = blockIdx.x;
    const int wave = threadIdx.x >> 6;
    const int lane = threadIdx.x & 63;
    const int r    = wave * HDIM + j;

    const float xg    = (lane == 0) ? Xg_t[r] : 0.0f;
    const float cprev = (threadIdx.x == 0) ? c[j] : 0.0f;

    const uint4*  Wr = Whh16 + (size_t)r * (HDIM / 8);
    const float4* h4 = (const float4*)h_in;

    float acc = 0.0f;
    #pragma unroll
    for (int it = 0; it < 8; ++it) {
        const int g = it * 64 + lane;          // group of 8 elements
        uint4 wraw = Wr[g];
        const __half2* wh = (const __half2*)&wraw;
        const float4 ha = h4[2 * g];
        const float4 hb = h4[2 * g + 1];
        const float2 w0 = __half22float2(wh[0]);
        const float2 w1 = __half22float2(wh[1]);
        const float2 w2 = __half22float2(wh[2]);
        const float2 w3 = __half22float2(wh[3]);
        acc += w0.x * ha.x + w0.y * ha.y + w1.x * ha.z + w1.y * ha.w
             + w2.x * hb.x + w2.y * hb.y + w3.x * hb.z + w3.y * hb.w;
    }
    #pragma unroll
    for (int off = 32; off > 0; off >>= 1) acc += __shfl_xor(acc, off, 64);

    __shared__ float gate[4];
    if (lane == 0) gate[wave] = acc + xg;
    __syncthreads();

    if (threadIdx.x == 0) {
        const float gi = gate[0], gf = gate[1], gg = gate[2], go = gate[3];
        const float cj = sigmoidf_(gf) * cprev + sigmoidf_(gi) * tanhf(gg);
        const float hj = sigmoidf_(go) * tanhf(cj);
        c[j] = cj;
        h_out[j] = hj;
        if (final_out) { final_out[j] = cj; final_out[HDIM + j] = hj; }
    }
}

// ---------------- recurrent step, fp32 weights (fallback) ----------------
__global__ __launch_bounds__(256) void lstm_step_f32(
        const float* __restrict__ Xg_t,
        const float* __restrict__ Whh,    // [H4, HDIM]
        const float* __restrict__ h_in,
        float* __restrict__ h_out,
        float* __restrict__ c,
        float* __restrict__ final_out)
{
    const int j    = blockIdx.x;
    const int wave = threadIdx.x >> 6;
    const int lane = threadIdx.x & 63;
    const int r    = wave * HDIM + j;

    const float xg    = (lane == 0) ? Xg_t[r] : 0.0f;
    const float cprev = (threadIdx.x == 0) ? c[j] : 0.0f;

    const float4* Wr = (const float4*)(Whh + (size_t)r * HDIM);
    const float4* h4 = (const float4*)h_in;

    float acc = 0.0f;
    #pragma unroll
    for (int it = 0; it < 16; ++it) {
        const int k4 = it * 64 + lane;
        const float4 w = Wr[k4];
        const float4 h = h4[k4];
        acc += w.x * h.x + w.y * h.y + w.z * h.z + w.w * h.w;
    }
    #pragma unroll
    for (int off = 32; off > 0; off >>= 1) acc += __shfl_xor(acc, off, 64);

    __shared__ float gate[4];
    if (lane == 0) gate[wave] = acc + xg;
    __syncthreads();

    if (threadIdx.x == 0) {
        const float gi = gate[0], gf = gate[1], gg = gate[2], go = gate[3];
        const float cj = sigmoidf_(gf) * cprev + sigmoidf_(gi) * tanhf(gg);
        const float hj = sigmoidf_(go) * tanhf(cj);
        c[j] = cj;
        h_out[j] = hj;
        if (final_out) { final_out[j] = cj; final_out[HDIM + j] = hj; }
    }
}

extern "C" void kernel_launch(void* const* d_in, const int* in_sizes, int n_in,
                              void* d_out, int out_size, void* d_ws, size_t ws_size,
                              hipStream_t stream) {
    const float* x    = (const float*)d_in[0];
    const int*   ei   = (const int*)  d_in[1];
    const float* ew   = (const float*)d_in[2];
    const float* Wg   = (const float*)d_in[3];
    const float* bg   = (const float*)d_in[4];
    const float* Wih  = (const float*)d_in[5];
    const float* Whh  = (const float*)d_in[6];
    const float* b_ih = (const float*)d_in[7];
    const float* b_hh = (const float*)d_in[8];
    float* out = (float*)d_out;

    const size_t fp16_bytes  = (size_t)H4 * HDIM * sizeof(__half);        // 128 MiB
    const size_t float_elems = (size_t)T_STEPS * HDIM * 3  // feats, hs_g, acc_g
                             + (size_t)T_STEPS * N_NODES   // deg_g
                             + (size_t)T_STEPS * H4        // Xg
                             + 3 * HDIM;                   // hA, hB, c
    const bool   use_fp16    = ws_size >= fp16_bytes + float_elems * sizeof(float);

    char*  base  = (char*)d_ws;
    uint4* Whh16 = (uint4*)base;                                          // fp16 copy (or unused)
    float* fbase = use_fp16 ? (float*)(base + fp16_bytes) : (float*)base;
    float* feats = fbase;                       // T*HDIM
    float* hs_g  = feats + T_STEPS * HDIM;      // T*HDIM
    float* acc_g = hs_g + T_STEPS * HDIM;       // T*HDIM
    float* deg_g = acc_g + T_STEPS * HDIM;      // T*N
    float* Xg    = deg_g + T_STEPS * N_NODES;   // T*H4
    float* hA    = Xg + T_STEPS * H4;           // HDIM
    float* hB    = hA + HDIM;                   // HDIM
    float* c     = hB + HDIM;                   // HDIM

    // GCN: 4-phase, 192 blocks each (cross-block deg dependency = dispatch boundary)
    gcn_hs_init<<<T_STEPS * HDIM / 256, 256, 0, stream>>>(x, Wg, hs_g, deg_g, acc_g);
    gcn_deg    <<<T_STEPS * KSPLIT,     256, 0, stream>>>(ei, ew, deg_g);
    gcn_scatter<<<T_STEPS * KSPLIT,     256, 0, stream>>>(ei, ew, hs_g, deg_g, acc_g);
    gcn_final  <<<T_STEPS * HDIM / 256, 256, 0, stream>>>(acc_g, hs_g, deg_g, bg, feats);

    wih_gemm<<<H4 / 8, 256, 0, stream>>>(feats, Wih, b_ih, b_hh, Xg);

    // step 0: h0 = c0 = 0 -> no GEMV
    lstm_step0<<<HDIM / 256, 256, 0, stream>>>(Xg, hA, c);

    float* hin = hA;
    float* hout = hB;
    if (use_fp16) {
        lstm_step_cvt<<<HDIM, 256, 0, stream>>>(Xg + (size_t)1 * H4, Whh, Whh16, hin, hout, c);
        { float* tmp = hin; hin = hout; hout = tmp; }
        for (int t = 2; t < T_STEPS; ++t) {
            float* fout = (t == T_STEPS - 1) ? out : nullptr;
            lstm_step_f16<<<HDIM, 256, 0, stream>>>(Xg + (size_t)t * H4, Whh16, hin, hout, c, fout);
            float* tmp = hin; hin = hout; hout = tmp;
        }
    } else {
        for (int t = 1; t < T_STEPS; ++t) {
            float* fout = (t == T_STEPS - 1) ? out : nullptr;
            lstm_step_f32<<<HDIM, 256, 0, stream>>>(Xg + (size_t)t * H4, Whh, hin, hout, c, fout);
            float* tmp = hin; hin = hout; hout = tmp;
        }
    }
}